// Round 1
// baseline (105.591 us; speedup 1.0000x reference)
//
#include <hip/hip_runtime.h>
#include <hip/hip_bf16.h>

// WaveletProductLayer: out[b,n] = prod_d psi((x[b,d]-c[n,d])/s[n,d])
// psi(z) = (1 - z^2) * exp(-0.5 z^2)
// Factorization: prod psi = [prod (1-z^2)] * exp(-0.5 * sum z^2), applied
// per group of 16 d's to avoid fp32 overflow of the bare product
// (|1-z^2|^16 < 2^128 requires |z| < 16; data max |z| ~ 8.7).
//
// Precompute cp = c/s, rs = 1/s into d_ws so the inner step is:
//   z = fma(x, rs, -cp); t = fma(-z,z,1); p *= t; s2 = fma(z,z,s2)
// => 4 VALU ops/element. cp/rs addresses are block-uniform -> scalar loads.

#define DD 64
#define NT 16   // n-chunk per block (res regs per thread)

__global__ void prep_pairs(const float* __restrict__ c,
                           const float* __restrict__ s,
                           float2* __restrict__ pairs, int total) {
    int i = blockIdx.x * 256 + threadIdx.x;
    if (i < total) {
        float rs = 1.0f / s[i];
        pairs[i] = make_float2(c[i] * rs, rs);  // {cp, rs}
    }
}

__global__ __launch_bounds__(256, 4)
void wavelet_kernel(const float* __restrict__ x,
                    const float2* __restrict__ pairs,
                    float* __restrict__ out, int B, int N) {
    int b = blockIdx.x * 256 + threadIdx.x;
    if (b >= B) return;
    int n0 = blockIdx.y * NT;

    // x row into registers (64 VGPRs), 16B vector loads
    float xr[DD];
    const float4* xv = (const float4*)(x + (size_t)b * DD);
#pragma unroll
    for (int i = 0; i < DD / 4; ++i) {
        float4 t = xv[i];
        xr[4 * i + 0] = t.x; xr[4 * i + 1] = t.y;
        xr[4 * i + 2] = t.z; xr[4 * i + 3] = t.w;
    }

    float res[NT];
#pragma unroll
    for (int j = 0; j < NT; ++j) {
        const float2* pp = pairs + (size_t)(n0 + j) * DD;  // block-uniform
        float acc = 1.0f;
#pragma unroll
        for (int g = 0; g < DD / 16; ++g) {
            float p = 1.0f;
            float s2 = 0.0f;
#pragma unroll
            for (int k = 0; k < 16; ++k) {
                int d = g * 16 + k;
                float2 pr = pp[d];                       // uniform -> s_load
                float z = __builtin_fmaf(xr[d], pr.y, -pr.x);
                p *= (1.0f - z * z);
                s2 = __builtin_fmaf(z, z, s2);
            }
            acc *= p * __expf(-0.5f * s2);
        }
        res[j] = acc;
    }

    // contiguous 64B per thread
    float4* op = (float4*)(out + (size_t)b * N + n0);
#pragma unroll
    for (int j = 0; j < NT / 4; ++j)
        op[j] = make_float4(res[4 * j], res[4 * j + 1],
                            res[4 * j + 2], res[4 * j + 3]);
}

extern "C" void kernel_launch(void* const* d_in, const int* in_sizes, int n_in,
                              void* d_out, int out_size, void* d_ws, size_t ws_size,
                              hipStream_t stream) {
    const float* x = (const float*)d_in[0];
    const float* c = (const float*)d_in[1];
    const float* s = (const float*)d_in[2];
    float* out = (float*)d_out;

    int B = in_sizes[0] / DD;   // 8192
    int total = in_sizes[1];    // N*D = 32768
    int N = total / DD;         // 512

    float2* pairs = (float2*)d_ws;  // needs N*D*8 = 256 KB of workspace

    prep_pairs<<<(total + 255) / 256, 256, 0, stream>>>(c, s, pairs, total);

    dim3 grid((B + 255) / 256, N / NT);
    wavelet_kernel<<<grid, 256, 0, stream>>>(x, pairs, out, B, N);
}